// Round 11
// baseline (368.163 us; speedup 1.0000x reference)
//
#include <hip/hip_runtime.h>

typedef _Float16 f16x8 __attribute__((ext_vector_type(8)));
typedef _Float16 f16x4 __attribute__((ext_vector_type(4)));
typedef _Float16 f16x2 __attribute__((ext_vector_type(2)));
typedef float f32x4 __attribute__((ext_vector_type(4)));

#define NB_   8
#define NN_   2000
#define TT_   64
#define FF_   32
#define HH_   128
#define EE_   32000
#define RSTR  192        // swizzled LDS row stride (f16 elems)
#define NODES 64         // nodes per block (1 block/CU, 250 lstm blocks)

__device__ __forceinline__ float fexp2(float v) { return __builtin_amdgcn_exp2f(v); }
__device__ __forceinline__ float frcp(float v)  { return __builtin_amdgcn_rcpf(v); }

// ---- fused LSTM + GCN-GEMM + (hidden) CSR build. 251 blocks x 512 thr.
// Byte-identical to round 10 (best measured: 211.8us, no spill, CSR hidden).
__global__ __launch_bounds__(512, 2) void lstm_gcn_kernel(
    const float* __restrict__ x,
    const float* __restrict__ Wih, const float* __restrict__ Whh,
    const float* __restrict__ bih, const float* __restrict__ bhh,
    const float* __restrict__ gcnW, const int* __restrict__ ei,
    _Float16* __restrict__ xwT,
    int* __restrict__ offs, float* __restrict__ deg, float* __restrict__ dinv,
    int* __restrict__ csr_src, float* __restrict__ csr_w) {
  __shared__ char smem[32768];

  if (blockIdx.x == 250) {
    // ---- CSR builder block (512 threads, one CU, hidden under lstm blocks)
    int* hist = (int*)smem;          // 2048 ints
    int* s0   = hist + 2048;
    int* s1   = s0 + 2048;
    float* dinvL = (float*)(s1 + 2048);
    const int t = threadIdx.x;
    for (int i = t; i < 2048; i += 512) hist[i] = (i < NN_) ? 1 : 0;   // self-loop
    __syncthreads();
    for (int e = t; e < EE_; e += 512) atomicAdd(&hist[ei[EE_ + e]], 1);
    __syncthreads();
    for (int i = t; i < 2048; i += 512) s0[i] = (i < NN_) ? (hist[i] - 1) : 0;
    __syncthreads();
    int* src = s0; int* dst = s1;
    for (int off = 1; off < 2048; off <<= 1) {
      for (int i = t; i < 2048; i += 512)
        dst[i] = src[i] + ((i >= off) ? src[i - off] : 0);
      __syncthreads();
      int* tmp = src; src = dst; dst = tmp;
    }
    int* cur = dst;   // the buffer not holding the final scan
    for (int i = t; i < NN_; i += 512) {
      int dgi = hist[i];
      int exc = src[i] - (dgi - 1);   // exclusive scan of (deg-1)
      offs[i] = exc;
      cur[i] = exc;
      deg[i] = (float)dgi;
      float dv = __builtin_amdgcn_rsqf((float)dgi);   // dgi >= 1 (self-loop)
      dinvL[i] = dv;
      dinv[i] = dv;
    }
    __syncthreads();
    for (int e = t; e < EE_; e += 512) {
      int s = ei[e], d = ei[EE_ + e];
      int pos = atomicAdd(&cur[d], 1);
      csr_src[pos] = s;
      csr_w[pos] = dinvL[s] * dinvL[d];
    }
    return;
  }

  _Float16* A = (_Float16*)smem;            // 24576 B activation tile
  const int tid  = threadIdx.x;
  const int wave = tid >> 6;                // 0..7
  const int lane = tid & 63;
  const int n15  = lane & 15;
  const int q    = lane >> 4;
  const int m    = n15 & 7;
  const int hm   = m >> 2;
  const int qx   = q ^ (m & 3);
  const int node0 = blockIdx.x * NODES;

  // self-pack weight fragments (prep-kernel arithmetic, inline):
  // gate rows i,f,o scaled by -1.44269504; g rows by -2.88539008.
  f16x8 Af[4][4];   // Whh part, K 32..159
  f16x8 Ax[4];      // Wih part, K 0..31
  f32x4 Bz[4];      // (bih+bhh) scaled
#pragma unroll
  for (int g = 0; g < 4; ++g) {
    const float sc = (g == 2) ? -2.88539008f : -1.44269504f;
    const int row = g * 128 + wave * 16 + n15;
    {
      const float4* wi = (const float4*)(Wih + row * 32 + q * 8);
      float4 a0 = wi[0], a1 = wi[1];
      Ax[g] = (f16x8){(_Float16)(a0.x * sc), (_Float16)(a0.y * sc),
                      (_Float16)(a0.z * sc), (_Float16)(a0.w * sc),
                      (_Float16)(a1.x * sc), (_Float16)(a1.y * sc),
                      (_Float16)(a1.z * sc), (_Float16)(a1.w * sc)};
    }
#pragma unroll
    for (int kc = 1; kc < 5; ++kc) {
      const float4* wh = (const float4*)(Whh + row * 128 + (kc - 1) * 32 + q * 8);
      float4 a0 = wh[0], a1 = wh[1];
      Af[g][kc - 1] = (f16x8){(_Float16)(a0.x * sc), (_Float16)(a0.y * sc),
                              (_Float16)(a0.z * sc), (_Float16)(a0.w * sc),
                              (_Float16)(a1.x * sc), (_Float16)(a1.y * sc),
                              (_Float16)(a1.z * sc), (_Float16)(a1.w * sc)};
    }
    {
      const int bo = g * 128 + wave * 16 + q * 4;
      float4 bi = *(const float4*)(bih + bo);
      float4 bh = *(const float4*)(bhh + bo);
      Bz[g] = (f32x4){(bi.x + bh.x) * sc, (bi.y + bh.y) * sc,
                      (bi.z + bh.z) * sc, (bi.w + bh.w) * sc};
    }
  }

  // per-lane LDS offsets (activation tile, XOR swizzle: physical group = logical ^ (row&7))
  const int bRow = n15 * RSTR + (qx << 3);   // + ((kc^hm)<<5) + nt*16*RSTR
  const int hOff = n15 * RSTR + (((4 + 2 * wave + (q >> 1)) ^ m) << 3) + ((q & 1) << 2);

  // x staging: thread stages 4 floats of one node-row per step
  const int xrow = tid >> 3;          // 0..63
  const int xf   = (tid & 7) * 4;     // 0,4,...,28
  const int xOff = xrow * RSTR + (((xf >> 3) ^ (xrow & 7)) << 3) + (xf & 7);
  const float* xb = x + (size_t)(node0 + xrow) * (TT_ * FF_) + xf;

  // h = 0 (64 rows x 16 h-groups = 1024 granules; 2 per thread)
#pragma unroll
  for (int j = 0; j < 2; ++j) {
    int idx = tid * 2 + j;
    int row = idx >> 4, ci = idx & 15;
    f16x8 z8 = {(_Float16)0, (_Float16)0, (_Float16)0, (_Float16)0,
                (_Float16)0, (_Float16)0, (_Float16)0, (_Float16)0};
    *(f16x8*)(A + row * RSTR + (((4 + ci) ^ (row & 7)) << 3)) = z8;
  }
  // stage x(0)
  {
    float4 v = *(const float4*)xb;
    f16x4 p = {(_Float16)v.x, (_Float16)v.y, (_Float16)v.z, (_Float16)v.w};
    *(f16x4*)(A + xOff) = p;
  }
  __syncthreads();

  f32x4 acc[4][4], c[4];
#pragma unroll
  for (int nt = 0; nt < 4; ++nt) c[nt] = (f32x4){0, 0, 0, 0};

  for (int t = 0; t < TT_; ++t) {
    // ---- MFMA phase: z = W·[x;h] + bias
    {
#pragma unroll
      for (int nt = 0; nt < 4; ++nt)
#pragma unroll
        for (int g = 0; g < 4; ++g) acc[nt][g] = Bz[g];
      __builtin_amdgcn_s_setprio(1);
#pragma unroll
      for (int nt = 0; nt < 4; ++nt) {
        f16x8 bf = *(const f16x8*)(A + nt * (16 * RSTR) + bRow + (hm << 5));  // kc=0
#pragma unroll
        for (int g = 0; g < 4; ++g)
          acc[nt][g] = __builtin_amdgcn_mfma_f32_16x16x32_f16(Ax[g], bf, acc[nt][g], 0, 0, 0);
      }
#pragma unroll
      for (int kc = 1; kc < 5; ++kc)
#pragma unroll
        for (int nt = 0; nt < 4; ++nt) {
          f16x8 bf = *(const f16x8*)(A + nt * (16 * RSTR) + bRow + ((kc ^ hm) << 5));
#pragma unroll
          for (int g = 0; g < 4; ++g)
            acc[nt][g] = __builtin_amdgcn_mfma_f32_16x16x32_f16(Af[g][kc - 1], bf, acc[nt][g], 0, 0, 0);
        }
      __builtin_amdgcn_s_setprio(0);
    }
    const bool more = (t + 1 < TT_);
    float4 xv;
    if (more) xv = *(const float4*)(xb + (t + 1) * FF_);
    __syncthreads();   // all LDS reads done before h/x writes

    // ---- gates phase: merged-denominator sigmoids (5 exp2 + 2 rcp per elem).
    // E* = exp2(pre-scaled z) = e^{-z} (g,c scaled by -2.885 -> e^{-2z}):
    //   c' = sf*c + si*tanh(g) = [c*(1+Ei)(1+Eg) + (1-Eg)(1+Ef)] / [(1+Ef)(1+Ei)(1+Eg)]
    //   h  = so*tanh(c')       = (1-Ec) / [(1+Ec)(1+Eo)]
#pragma unroll
    for (int nt = 0; nt < 4; ++nt) {
      f16x4 hp;
#pragma unroll
      for (int r = 0; r < 4; ++r) {
        float Ei = fexp2(acc[nt][0][r]);
        float Ef = fexp2(acc[nt][1][r]);
        float Eg = fexp2(acc[nt][2][r]);
        float Eo = fexp2(acc[nt][3][r]);
        float ai = 1.f + Ei, af = 1.f + Ef, ag = 1.f + Eg, ao = 1.f + Eo;
        float pig = ai * ag;
        float num = c[nt][r] * pig + (1.f - Eg) * af;
        float cn  = num * frcp(af * pig);
        c[nt][r] = cn;
        float Ec = fexp2(-2.88539008f * cn);
        float hn = (1.f - Ec) * frcp((1.f + Ec) * ao);
        hp[r] = (_Float16)hn;
      }
      *(f16x4*)(A + nt * (16 * RSTR) + hOff) = hp;
    }
    if (more) {
      f16x4 p = {(_Float16)xv.x, (_Float16)xv.y, (_Float16)xv.z, (_Float16)xv.w};
      *(f16x4*)(A + xOff) = p;
    }
    __syncthreads();
  }

  // ---- epilogue: xwT16[(n*8+b)*128 + col] = sum_k h[node][k] * gcnW[k][col], f16
  // Ag self-pack: Ag[kc][j] = gcnW[(kc*32+q*8+j)*128 + cg]  (strided; 64KB table, L2-hot)
  f16x8 Ag[4];
  {
    const int cg = wave * 16 + n15;
#pragma unroll
    for (int kc = 0; kc < 4; ++kc)
#pragma unroll
      for (int j = 0; j < 8; ++j)
        Ag[kc][j] = (_Float16)gcnW[(kc * 32 + q * 8 + j) * 128 + cg];
  }
  f32x4 acc2[4];
#pragma unroll
  for (int nt = 0; nt < 4; ++nt) acc2[nt] = (f32x4){0, 0, 0, 0};
  __builtin_amdgcn_s_setprio(1);
#pragma unroll
  for (int kc = 0; kc < 4; ++kc)
#pragma unroll
    for (int nt = 0; nt < 4; ++nt) {
      f16x8 bf = *(const f16x8*)(A + nt * (16 * RSTR) + bRow + (((kc + 1) ^ hm) << 5));
      acc2[nt] = __builtin_amdgcn_mfma_f32_16x16x32_f16(Ag[kc], bf, acc2[nt], 0, 0, 0);
    }
  __builtin_amdgcn_s_setprio(0);
#pragma unroll
  for (int nt = 0; nt < 4; ++nt) {
    int mnode = node0 + nt * 16 + n15;
    int b = mnode / NN_;
    int n = mnode - b * NN_;
    f16x4 hv = {(_Float16)acc2[nt][0], (_Float16)acc2[nt][1],
                (_Float16)acc2[nt][2], (_Float16)acc2[nt][3]};
    *(f16x4*)(xwT + ((size_t)n * 8 + b) * HH_ + wave * 16 + q * 4) = hv;
  }
}

// ---- fused CSR gather + MLP head, RESTRUCTURED: 250 blocks x 512 thr; each block
// owns 8 CONSECUTIVE nodes (2 groups of 256 threads x 4 sequential nodes). W1T is
// staged ONCE per block (was once per node: 2000 x 32KB re-stage = the dominant cost
// of the old 2000-block layout). Consecutive d per block => csr_src/csr_w reads are
// L2-contiguous across iterations. Per-node inner structure (b/dcol mapping, 4-edge
// unroll, (b,t) MLP mapping, 32-lane shfl reduce) unchanged => same accumulation
// order => absmax unchanged.
__global__ __launch_bounds__(512) void gathermlp_kernel(
    const _Float16* __restrict__ xwT, const int* __restrict__ offs,
    const float* __restrict__ deg, const float* __restrict__ dinv,
    const int* __restrict__ csr_src, const float* __restrict__ csr_w,
    const float* __restrict__ gcnb,
    const float* __restrict__ W1, const float* __restrict__ b1,
    const float* __restrict__ W2, const float* __restrict__ b2,
    float* __restrict__ out) {
  __shared__ float aggs[2][8][128];         // per-group node aggregate (8192 B)
  __shared__ float W1T[64][132];            // W1T[j][k] = W1[k*64+j]; pad 132 vs conflicts
  const int tid = threadIdx.x;
  const int grp = tid >> 8;                 // 0/1: which node-group
  const int tig = tid & 255;                // index within group
  for (int i = tid; i < 8192; i += 512) {
    int k = i >> 6, j = i & 63;
    W1T[j][k] = W1[i];
  }
  __syncthreads();

  const int b    = tig >> 5;                // batch 0..7
  const int t    = tig & 31;
  const int dcol = t * 4;                   // dim 0,4,...,124
  const int boff = b * 128 + dcol;          // f16 offset within 1024-elem node row
  const float4 bj = *(const float4*)(gcnb + dcol);
  const float acc1_0 = b1[t], acc2_0 = b1[t + 32];
  const float w2a = W2[t], w2b = W2[t + 32];

#pragma unroll 1
  for (int it = 0; it < 4; ++it) {
    const int d = blockIdx.x * 8 + grp * 4 + it;
    // ---- gather phase (256 threads of this group)
    {
      const int beg = offs[d];
      const int cnt = (int)deg[d] - 1;
      float a0 = 0.f, a1 = 0.f, a2 = 0.f, a3 = 0.f;
      int e = 0;
      for (; e + 3 < cnt; e += 4) {         // 4-edge unroll: 4 loads in flight
        int s0 = csr_src[beg + e],     s1 = csr_src[beg + e + 1];
        int s2 = csr_src[beg + e + 2], s3 = csr_src[beg + e + 3];
        float w0 = csr_w[beg + e],     w1 = csr_w[beg + e + 1];
        float w2 = csr_w[beg + e + 2], w3 = csr_w[beg + e + 3];
        f16x4 v0 = *(const f16x4*)(xwT + (size_t)s0 * 1024 + boff);
        f16x4 v1 = *(const f16x4*)(xwT + (size_t)s1 * 1024 + boff);
        f16x4 v2 = *(const f16x4*)(xwT + (size_t)s2 * 1024 + boff);
        f16x4 v3 = *(const f16x4*)(xwT + (size_t)s3 * 1024 + boff);
        a0 += w0 * (float)v0[0] + w1 * (float)v1[0] + w2 * (float)v2[0] + w3 * (float)v3[0];
        a1 += w0 * (float)v0[1] + w1 * (float)v1[1] + w2 * (float)v2[1] + w3 * (float)v3[1];
        a2 += w0 * (float)v0[2] + w1 * (float)v1[2] + w2 * (float)v2[2] + w3 * (float)v3[2];
        a3 += w0 * (float)v0[3] + w1 * (float)v1[3] + w2 * (float)v2[3] + w3 * (float)v3[3];
      }
      for (; e < cnt; ++e) {
        int s = csr_src[beg + e];
        float w = csr_w[beg + e];
        f16x4 v = *(const f16x4*)(xwT + (size_t)s * 1024 + boff);
        a0 += w * (float)v[0]; a1 += w * (float)v[1];
        a2 += w * (float)v[2]; a3 += w * (float)v[3];
      }
      {
        float di = dinv[d];
        float w = di * di;
        f16x4 v = *(const f16x4*)(xwT + (size_t)d * 1024 + boff);
        a0 += w * (float)v[0]; a1 += w * (float)v[1];
        a2 += w * (float)v[2]; a3 += w * (float)v[3];
      }
      *(float4*)&aggs[grp][b][dcol] =
          (float4){a0 + bj.x, a1 + bj.y, a2 + bj.z, a3 + bj.w};
    }
    __syncthreads();
    // ---- MLP phase: thread (b, t) owns hidden dims {t, t+32}
    {
      float acc1 = acc1_0, acc2 = acc2_0;
#pragma unroll 8
      for (int kc = 0; kc < 32; ++kc) {
        float4 a  = *(const float4*)&aggs[grp][b][kc * 4];
        float4 w1 = *(const float4*)&W1T[t][kc * 4];
        float4 w2 = *(const float4*)&W1T[t + 32][kc * 4];
        acc1 += a.x * w1.x + a.y * w1.y + a.z * w1.z + a.w * w1.w;
        acc2 += a.x * w2.x + a.y * w2.y + a.z * w2.z + a.w * w2.w;
      }
      float s1 = acc1 * frcp(1.f + fexp2(-1.44269504f * acc1));
      float s2 = acc2 * frcp(1.f + fexp2(-1.44269504f * acc2));
      float part = s1 * w2a + s2 * w2b;
#pragma unroll
      for (int msk = 16; msk >= 1; msk >>= 1) part += __shfl_xor(part, msk);
      if (t == 0) out[(size_t)b * NN_ + d] = part + b2[0];
    }
    if (it < 3) __syncthreads();   // aggs WAR: next gather overwrites after MLP reads
  }
}

extern "C" void kernel_launch(void* const* d_in, const int* in_sizes, int n_in,
                              void* d_out, int out_size, void* d_ws, size_t ws_size,
                              hipStream_t stream) {
  const float* x    = (const float*)d_in[0];
  const int*   ei   = (const int*)d_in[1];
  const float* Wih  = (const float*)d_in[2];
  const float* Whh  = (const float*)d_in[3];
  const float* bih  = (const float*)d_in[4];
  const float* bhh  = (const float*)d_in[5];
  const float* gcnW = (const float*)d_in[6];
  const float* gcnb = (const float*)d_in[7];
  const float* W1   = (const float*)d_in[8];
  const float* b1   = (const float*)d_in[9];
  const float* W2   = (const float*)d_in[10];
  const float* b2   = (const float*)d_in[11];
  float* out = (float*)d_out;
  char* ws = (char*)d_ws;

  _Float16* xwT    = (_Float16*)(ws + 198656);           // 4096000  [node][batch][128] f16
  float*    deg    = (float*)(ws + 8390656);             // 8192
  float*    dinv   = (float*)(ws + 8398848);             // 8192
  int*      offs   = (int*)(ws + 8407040);               // 8192
  int*      csrs   = (int*)(ws + 8423424);               // 128000
  float*    csrw   = (float*)(ws + 8551424);             // 128000

  lstm_gcn_kernel<<<251, 512, 0, stream>>>(x, Wih, Whh, bih, bhh, gcnW, ei,
                                           xwT, offs, deg, dinv, csrs, csrw);
  gathermlp_kernel<<<250, 512, 0, stream>>>(xwT, offs, deg, dinv, csrs, csrw,
                                            gcnb, W1, b1, W2, b2, out);
}

// Round 12
// 355.488 us; speedup vs baseline: 1.0357x; 1.0357x over previous
//
#include <hip/hip_runtime.h>

typedef _Float16 f16x8 __attribute__((ext_vector_type(8)));
typedef _Float16 f16x4 __attribute__((ext_vector_type(4)));
typedef _Float16 f16x2 __attribute__((ext_vector_type(2)));
typedef float f32x4 __attribute__((ext_vector_type(4)));

#define NB_   8
#define NN_   2000
#define TT_   64
#define FF_   32
#define HH_   128
#define EE_   32000
#define RSTR  192        // swizzled LDS row stride (f16 elems)
#define NODES 64         // nodes per block (1 block/CU, 250 lstm blocks)

__device__ __forceinline__ float fexp2(float v) { return __builtin_amdgcn_exp2f(v); }
__device__ __forceinline__ float frcp(float v)  { return __builtin_amdgcn_rcpf(v); }

// ---- fused LSTM + GCN-GEMM + (hidden) CSR build. 251 blocks x 512 thr.
// Byte-identical to round 10 (best measured: 211.8us, no spill, CSR hidden).
__global__ __launch_bounds__(512, 2) void lstm_gcn_kernel(
    const float* __restrict__ x,
    const float* __restrict__ Wih, const float* __restrict__ Whh,
    const float* __restrict__ bih, const float* __restrict__ bhh,
    const float* __restrict__ gcnW, const int* __restrict__ ei,
    _Float16* __restrict__ xwT,
    int* __restrict__ offs, float* __restrict__ deg, float* __restrict__ dinv,
    int* __restrict__ csr_src, float* __restrict__ csr_w) {
  __shared__ char smem[32768];

  if (blockIdx.x == 250) {
    // ---- CSR builder block (512 threads, one CU, hidden under lstm blocks)
    int* hist = (int*)smem;          // 2048 ints
    int* s0   = hist + 2048;
    int* s1   = s0 + 2048;
    float* dinvL = (float*)(s1 + 2048);
    const int t = threadIdx.x;
    for (int i = t; i < 2048; i += 512) hist[i] = (i < NN_) ? 1 : 0;   // self-loop
    __syncthreads();
    for (int e = t; e < EE_; e += 512) atomicAdd(&hist[ei[EE_ + e]], 1);
    __syncthreads();
    for (int i = t; i < 2048; i += 512) s0[i] = (i < NN_) ? (hist[i] - 1) : 0;
    __syncthreads();
    int* src = s0; int* dst = s1;
    for (int off = 1; off < 2048; off <<= 1) {
      for (int i = t; i < 2048; i += 512)
        dst[i] = src[i] + ((i >= off) ? src[i - off] : 0);
      __syncthreads();
      int* tmp = src; src = dst; dst = tmp;
    }
    int* cur = dst;   // the buffer not holding the final scan
    for (int i = t; i < NN_; i += 512) {
      int dgi = hist[i];
      int exc = src[i] - (dgi - 1);   // exclusive scan of (deg-1)
      offs[i] = exc;
      cur[i] = exc;
      deg[i] = (float)dgi;
      float dv = __builtin_amdgcn_rsqf((float)dgi);   // dgi >= 1 (self-loop)
      dinvL[i] = dv;
      dinv[i] = dv;
    }
    __syncthreads();
    for (int e = t; e < EE_; e += 512) {
      int s = ei[e], d = ei[EE_ + e];
      int pos = atomicAdd(&cur[d], 1);
      csr_src[pos] = s;
      csr_w[pos] = dinvL[s] * dinvL[d];
    }
    return;
  }

  _Float16* A = (_Float16*)smem;            // 24576 B activation tile
  const int tid  = threadIdx.x;
  const int wave = tid >> 6;                // 0..7
  const int lane = tid & 63;
  const int n15  = lane & 15;
  const int q    = lane >> 4;
  const int m    = n15 & 7;
  const int hm   = m >> 2;
  const int qx   = q ^ (m & 3);
  const int node0 = blockIdx.x * NODES;

  // self-pack weight fragments (prep-kernel arithmetic, inline):
  // gate rows i,f,o scaled by -1.44269504; g rows by -2.88539008.
  f16x8 Af[4][4];   // Whh part, K 32..159
  f16x8 Ax[4];      // Wih part, K 0..31
  f32x4 Bz[4];      // (bih+bhh) scaled
#pragma unroll
  for (int g = 0; g < 4; ++g) {
    const float sc = (g == 2) ? -2.88539008f : -1.44269504f;
    const int row = g * 128 + wave * 16 + n15;
    {
      const float4* wi = (const float4*)(Wih + row * 32 + q * 8);
      float4 a0 = wi[0], a1 = wi[1];
      Ax[g] = (f16x8){(_Float16)(a0.x * sc), (_Float16)(a0.y * sc),
                      (_Float16)(a0.z * sc), (_Float16)(a0.w * sc),
                      (_Float16)(a1.x * sc), (_Float16)(a1.y * sc),
                      (_Float16)(a1.z * sc), (_Float16)(a1.w * sc)};
    }
#pragma unroll
    for (int kc = 1; kc < 5; ++kc) {
      const float4* wh = (const float4*)(Whh + row * 128 + (kc - 1) * 32 + q * 8);
      float4 a0 = wh[0], a1 = wh[1];
      Af[g][kc - 1] = (f16x8){(_Float16)(a0.x * sc), (_Float16)(a0.y * sc),
                              (_Float16)(a0.z * sc), (_Float16)(a0.w * sc),
                              (_Float16)(a1.x * sc), (_Float16)(a1.y * sc),
                              (_Float16)(a1.z * sc), (_Float16)(a1.w * sc)};
    }
    {
      const int bo = g * 128 + wave * 16 + q * 4;
      float4 bi = *(const float4*)(bih + bo);
      float4 bh = *(const float4*)(bhh + bo);
      Bz[g] = (f32x4){(bi.x + bh.x) * sc, (bi.y + bh.y) * sc,
                      (bi.z + bh.z) * sc, (bi.w + bh.w) * sc};
    }
  }

  // per-lane LDS offsets (activation tile, XOR swizzle: physical group = logical ^ (row&7))
  const int bRow = n15 * RSTR + (qx << 3);   // + ((kc^hm)<<5) + nt*16*RSTR
  const int hOff = n15 * RSTR + (((4 + 2 * wave + (q >> 1)) ^ m) << 3) + ((q & 1) << 2);

  // x staging: thread stages 4 floats of one node-row per step
  const int xrow = tid >> 3;          // 0..63
  const int xf   = (tid & 7) * 4;     // 0,4,...,28
  const int xOff = xrow * RSTR + (((xf >> 3) ^ (xrow & 7)) << 3) + (xf & 7);
  const float* xb = x + (size_t)(node0 + xrow) * (TT_ * FF_) + xf;

  // h = 0 (64 rows x 16 h-groups = 1024 granules; 2 per thread)
#pragma unroll
  for (int j = 0; j < 2; ++j) {
    int idx = tid * 2 + j;
    int row = idx >> 4, ci = idx & 15;
    f16x8 z8 = {(_Float16)0, (_Float16)0, (_Float16)0, (_Float16)0,
                (_Float16)0, (_Float16)0, (_Float16)0, (_Float16)0};
    *(f16x8*)(A + row * RSTR + (((4 + ci) ^ (row & 7)) << 3)) = z8;
  }
  // stage x(0)
  {
    float4 v = *(const float4*)xb;
    f16x4 p = {(_Float16)v.x, (_Float16)v.y, (_Float16)v.z, (_Float16)v.w};
    *(f16x4*)(A + xOff) = p;
  }
  __syncthreads();

  f32x4 acc[4][4], c[4];
#pragma unroll
  for (int nt = 0; nt < 4; ++nt) c[nt] = (f32x4){0, 0, 0, 0};

  for (int t = 0; t < TT_; ++t) {
    // ---- MFMA phase: z = W·[x;h] + bias
    {
#pragma unroll
      for (int nt = 0; nt < 4; ++nt)
#pragma unroll
        for (int g = 0; g < 4; ++g) acc[nt][g] = Bz[g];
      __builtin_amdgcn_s_setprio(1);
#pragma unroll
      for (int nt = 0; nt < 4; ++nt) {
        f16x8 bf = *(const f16x8*)(A + nt * (16 * RSTR) + bRow + (hm << 5));  // kc=0
#pragma unroll
        for (int g = 0; g < 4; ++g)
          acc[nt][g] = __builtin_amdgcn_mfma_f32_16x16x32_f16(Ax[g], bf, acc[nt][g], 0, 0, 0);
      }
#pragma unroll
      for (int kc = 1; kc < 5; ++kc)
#pragma unroll
        for (int nt = 0; nt < 4; ++nt) {
          f16x8 bf = *(const f16x8*)(A + nt * (16 * RSTR) + bRow + ((kc ^ hm) << 5));
#pragma unroll
          for (int g = 0; g < 4; ++g)
            acc[nt][g] = __builtin_amdgcn_mfma_f32_16x16x32_f16(Af[g][kc - 1], bf, acc[nt][g], 0, 0, 0);
        }
      __builtin_amdgcn_s_setprio(0);
    }
    const bool more = (t + 1 < TT_);
    float4 xv;
    if (more) xv = *(const float4*)(xb + (t + 1) * FF_);
    __syncthreads();   // all LDS reads done before h/x writes

    // ---- gates phase: merged-denominator sigmoids (5 exp2 + 2 rcp per elem).
    // E* = exp2(pre-scaled z) = e^{-z} (g,c scaled by -2.885 -> e^{-2z}):
    //   c' = sf*c + si*tanh(g) = [c*(1+Ei)(1+Eg) + (1-Eg)(1+Ef)] / [(1+Ef)(1+Ei)(1+Eg)]
    //   h  = so*tanh(c')       = (1-Ec) / [(1+Ec)(1+Eo)]
#pragma unroll
    for (int nt = 0; nt < 4; ++nt) {
      f16x4 hp;
#pragma unroll
      for (int r = 0; r < 4; ++r) {
        float Ei = fexp2(acc[nt][0][r]);
        float Ef = fexp2(acc[nt][1][r]);
        float Eg = fexp2(acc[nt][2][r]);
        float Eo = fexp2(acc[nt][3][r]);
        float ai = 1.f + Ei, af = 1.f + Ef, ag = 1.f + Eg, ao = 1.f + Eo;
        float pig = ai * ag;
        float num = c[nt][r] * pig + (1.f - Eg) * af;
        float cn  = num * frcp(af * pig);
        c[nt][r] = cn;
        float Ec = fexp2(-2.88539008f * cn);
        float hn = (1.f - Ec) * frcp((1.f + Ec) * ao);
        hp[r] = (_Float16)hn;
      }
      *(f16x4*)(A + nt * (16 * RSTR) + hOff) = hp;
    }
    if (more) {
      f16x4 p = {(_Float16)xv.x, (_Float16)xv.y, (_Float16)xv.z, (_Float16)xv.w};
      *(f16x4*)(A + xOff) = p;
    }
    __syncthreads();
  }

  // ---- epilogue: xwT16[(n*8+b)*128 + col] = sum_k h[node][k] * gcnW[k][col], f16
  // Ag self-pack: Ag[kc][j] = gcnW[(kc*32+q*8+j)*128 + cg]  (strided; 64KB table, L2-hot)
  f16x8 Ag[4];
  {
    const int cg = wave * 16 + n15;
#pragma unroll
    for (int kc = 0; kc < 4; ++kc)
#pragma unroll
      for (int j = 0; j < 8; ++j)
        Ag[kc][j] = (_Float16)gcnW[(kc * 32 + q * 8 + j) * 128 + cg];
  }
  f32x4 acc2[4];
#pragma unroll
  for (int nt = 0; nt < 4; ++nt) acc2[nt] = (f32x4){0, 0, 0, 0};
  __builtin_amdgcn_s_setprio(1);
#pragma unroll
  for (int kc = 0; kc < 4; ++kc)
#pragma unroll
    for (int nt = 0; nt < 4; ++nt) {
      f16x8 bf = *(const f16x8*)(A + nt * (16 * RSTR) + bRow + (((kc + 1) ^ hm) << 5));
      acc2[nt] = __builtin_amdgcn_mfma_f32_16x16x32_f16(Ag[kc], bf, acc2[nt], 0, 0, 0);
    }
  __builtin_amdgcn_s_setprio(0);
#pragma unroll
  for (int nt = 0; nt < 4; ++nt) {
    int mnode = node0 + nt * 16 + n15;
    int b = mnode / NN_;
    int n = mnode - b * NN_;
    f16x4 hv = {(_Float16)acc2[nt][0], (_Float16)acc2[nt][1],
                (_Float16)acc2[nt][2], (_Float16)acc2[nt][3]};
    *(f16x4*)(xwT + ((size_t)n * 8 + b) * HH_ + wave * 16 + q * 4) = hv;
  }
}

// ---- fused CSR gather + MLP head. 1000 blocks x 256 thr, 2 sequential nodes/block.
// Round-11 lesson: this kernel is TLP-bound (250 big blocks with 4-deep serial node
// loop regressed). This keeps round-10's per-CU node parallelism (~4 independent
// 256-thread units/CU) while halving W1T staging, and stages W1T as F16: staging
// traffic 64 -> 16 MB total, LDS 37.8 -> 20.9 KB -> 7 blocks/CU (was 4) for better
// latency hiding. Per-node inner structure (b/dcol mapping, 4-edge unroll, (b,t)
// MLP mapping, 32-lane shfl reduce) unchanged.
__global__ __launch_bounds__(256) void gathermlp_kernel(
    const _Float16* __restrict__ xwT, const int* __restrict__ offs,
    const float* __restrict__ deg, const float* __restrict__ dinv,
    const int* __restrict__ csr_src, const float* __restrict__ csr_w,
    const float* __restrict__ gcnb,
    const float* __restrict__ W1, const float* __restrict__ b1,
    const float* __restrict__ W2, const float* __restrict__ b2,
    float* __restrict__ out) {
  __shared__ float aggs[8][128];            // 4096 B
  __shared__ _Float16 W1T[64][132];         // f16; [j][k] = W1[k*64+j]; 16896 B
  const int tid = threadIdx.x;
  for (int i = tid; i < 8192; i += 256) {
    int k = i >> 6, j = i & 63;
    W1T[j][k] = (_Float16)W1[i];
  }

  const int b    = tid >> 5;                // batch 0..7
  const int t    = tid & 31;
  const int dcol = t * 4;                   // dim 0,4,...,124
  const int boff = b * 128 + dcol;          // f16 offset within 1024-elem node row
  const float4 bj = *(const float4*)(gcnb + dcol);
  const float acc1_0 = b1[t], acc2_0 = b1[t + 32];
  const float w2a = W2[t], w2b = W2[t + 32];
  __syncthreads();

#pragma unroll 1
  for (int it = 0; it < 2; ++it) {
    const int d = blockIdx.x * 2 + it;
    // ---- gather phase
    {
      const int beg = offs[d];
      const int cnt = (int)deg[d] - 1;
      float a0 = 0.f, a1 = 0.f, a2 = 0.f, a3 = 0.f;
      int e = 0;
      for (; e + 3 < cnt; e += 4) {         // 4-edge unroll: 4 loads in flight
        int s0 = csr_src[beg + e],     s1 = csr_src[beg + e + 1];
        int s2 = csr_src[beg + e + 2], s3 = csr_src[beg + e + 3];
        float w0 = csr_w[beg + e],     w1 = csr_w[beg + e + 1];
        float w2 = csr_w[beg + e + 2], w3 = csr_w[beg + e + 3];
        f16x4 v0 = *(const f16x4*)(xwT + (size_t)s0 * 1024 + boff);
        f16x4 v1 = *(const f16x4*)(xwT + (size_t)s1 * 1024 + boff);
        f16x4 v2 = *(const f16x4*)(xwT + (size_t)s2 * 1024 + boff);
        f16x4 v3 = *(const f16x4*)(xwT + (size_t)s3 * 1024 + boff);
        a0 += w0 * (float)v0[0] + w1 * (float)v1[0] + w2 * (float)v2[0] + w3 * (float)v3[0];
        a1 += w0 * (float)v0[1] + w1 * (float)v1[1] + w2 * (float)v2[1] + w3 * (float)v3[1];
        a2 += w0 * (float)v0[2] + w1 * (float)v1[2] + w2 * (float)v2[2] + w3 * (float)v3[2];
        a3 += w0 * (float)v0[3] + w1 * (float)v1[3] + w2 * (float)v2[3] + w3 * (float)v3[3];
      }
      for (; e < cnt; ++e) {
        int s = csr_src[beg + e];
        float w = csr_w[beg + e];
        f16x4 v = *(const f16x4*)(xwT + (size_t)s * 1024 + boff);
        a0 += w * (float)v[0]; a1 += w * (float)v[1];
        a2 += w * (float)v[2]; a3 += w * (float)v[3];
      }
      {
        float di = dinv[d];
        float w = di * di;
        f16x4 v = *(const f16x4*)(xwT + (size_t)d * 1024 + boff);
        a0 += w * (float)v[0]; a1 += w * (float)v[1];
        a2 += w * (float)v[2]; a3 += w * (float)v[3];
      }
      *(float4*)&aggs[b][dcol] = (float4){a0 + bj.x, a1 + bj.y, a2 + bj.z, a3 + bj.w};
    }
    __syncthreads();
    // ---- MLP phase: thread (b, t) owns hidden dims {t, t+32}
    {
      float acc1 = acc1_0, acc2 = acc2_0;
#pragma unroll 8
      for (int kc = 0; kc < 32; ++kc) {
        float4 a  = *(const float4*)&aggs[b][kc * 4];
        f16x4 w1 = *(const f16x4*)&W1T[t][kc * 4];
        f16x4 w2 = *(const f16x4*)&W1T[t + 32][kc * 4];
        acc1 += a.x * (float)w1[0] + a.y * (float)w1[1] + a.z * (float)w1[2] + a.w * (float)w1[3];
        acc2 += a.x * (float)w2[0] + a.y * (float)w2[1] + a.z * (float)w2[2] + a.w * (float)w2[3];
      }
      float s1 = acc1 * frcp(1.f + fexp2(-1.44269504f * acc1));
      float s2 = acc2 * frcp(1.f + fexp2(-1.44269504f * acc2));
      float part = s1 * w2a + s2 * w2b;
#pragma unroll
      for (int msk = 16; msk >= 1; msk >>= 1) part += __shfl_xor(part, msk);
      if (t == 0) out[(size_t)b * NN_ + d] = part + b2[0];
    }
    if (it == 0) __syncthreads();   // aggs WAR: next gather overwrites after MLP reads
  }
}

extern "C" void kernel_launch(void* const* d_in, const int* in_sizes, int n_in,
                              void* d_out, int out_size, void* d_ws, size_t ws_size,
                              hipStream_t stream) {
  const float* x    = (const float*)d_in[0];
  const int*   ei   = (const int*)d_in[1];
  const float* Wih  = (const float*)d_in[2];
  const float* Whh  = (const float*)d_in[3];
  const float* bih  = (const float*)d_in[4];
  const float* bhh  = (const float*)d_in[5];
  const float* gcnW = (const float*)d_in[6];
  const float* gcnb = (const float*)d_in[7];
  const float* W1   = (const float*)d_in[8];
  const float* b1   = (const float*)d_in[9];
  const float* W2   = (const float*)d_in[10];
  const float* b2   = (const float*)d_in[11];
  float* out = (float*)d_out;
  char* ws = (char*)d_ws;

  _Float16* xwT    = (_Float16*)(ws + 198656);           // 4096000  [node][batch][128] f16
  float*    deg    = (float*)(ws + 8390656);             // 8192
  float*    dinv   = (float*)(ws + 8398848);             // 8192
  int*      offs   = (int*)(ws + 8407040);               // 8192
  int*      csrs   = (int*)(ws + 8423424);               // 128000
  float*    csrw   = (float*)(ws + 8551424);             // 128000

  lstm_gcn_kernel<<<251, 512, 0, stream>>>(x, Wih, Whh, bih, bhh, gcnW, ei,
                                           xwT, offs, deg, dinv, csrs, csrw);
  gathermlp_kernel<<<1000, 256, 0, stream>>>(xwT, offs, deg, dinv, csrs, csrw,
                                             gcnb, W1, b1, W2, b2, out);
}